// Round 6
// baseline (117.415 us; speedup 1.0000x reference)
//
#include <hip/hip_runtime.h>
#include <stdint.h>
#include <stddef.h>

// Problem: out[b,a,o] = sum_{i,j} h0[b,a,i] h1[b,a,j] T[a,i,j,o], h=concat(x,1)
// GEMM form: C[b,o] += G[b,k]*Tb[a,k,o]; main k=j*128+i (i,j<128); k=16384+c:
// G=h1[c]; k=16512+c: G=h0[c]; k=16640: G=1. 261 K-tiles of 64.
#define NA     4
#define DDIM   128
#define OUTD   128
#define BM     128
#define BN     128
#define NTILES 261
#define TILE_B 16384          // BN * 64 * 2B
#define OUT_ELEMS (4096 * NA * OUTD)   // 2,097,152 f32

typedef _Float16 f16;
typedef __attribute__((ext_vector_type(8)))  _Float16 f16x8;
typedef __attribute__((ext_vector_type(4)))  float    f32x4;
typedef __attribute__((ext_vector_type(16))) float    f32x16;

static const size_t TB_BYTES  = (size_t)NA * NTILES * TILE_B;          // 17,104,896
static const size_t P_BYTES   = (size_t)4 * OUT_ELEMS * sizeof(float); // 33,554,432
static const size_t WS_NEEDED = TB_BYTES + P_BYTES;                    // ~50.7 MB

// ---------------------------------------------------------------------------
// Prep: T f32 -> Tb f16, per (a,tile) a 16KB image; unit v = w*128+col
// (w=0..7) holds k = tile*64 + w*8 + e at output-col `col`.
// ---------------------------------------------------------------------------
__global__ __launch_bounds__(256) void prep_kernel(const float* __restrict__ T,
                                                   f16* __restrict__ Tb) {
    int blk  = blockIdx.x;            // a*NTILES + tile
    int a    = blk / NTILES;
    int tile = blk - a * NTILES;
    int t    = threadIdx.x;
    f16* base = Tb + (size_t)blk * (TILE_B / 2);
    #pragma unroll
    for (int u = 0; u < 4; ++u) {
        int v   = t + u * 256;
        int w   = v >> 7;
        int col = v & 127;
        f16x8 ov;
        #pragma unroll
        for (int e = 0; e < 8; ++e) {
            int k = tile * 64 + w * 8 + e;
            int i = -1, j = 0;
            if (k < 16384)       { i = k & 127;   j = k >> 7;    }
            else if (k < 16512)  { i = 128;       j = k - 16384; }
            else if (k < 16640)  { i = k - 16512; j = 128;       }
            else if (k == 16640) { i = 128;       j = 128;       }
            float val = 0.f;
            if (i >= 0) val = T[(((size_t)a * 129 + i) * 129 + j) * 128 + col];
            ov[e] = (f16)val;
        }
        *(f16x8*)(base + (size_t)v * 8) = ov;
    }
}

// ---------------------------------------------------------------------------
// GEMM: BM=128 x BN=128, 4 waves (1M x 4N, wave = 128 rows x 32 cols).
// B fragments loaded DIRECTLY global->registers (prep layout == fragment
// layout; 2x512B coalesced segments per load, L2-resident stream).
// No LDS B-staging, no loop barriers: waves free-run; register double
// buffer prefetches 2 tiles ahead; compiler inserts exact vmcnt waits.
// A built in registers (h0reg stationary, h1 scalar from 16KB LDS).
// ---------------------------------------------------------------------------
template <bool ATOMIC>
__global__ __launch_bounds__(256, 2) void gemm_kernel(const float* __restrict__ x0,
                                                      const float* __restrict__ x1,
                                                      const f16* __restrict__ Tb,
                                                      float* __restrict__ dst) {
    __shared__ __align__(16) f16 h1t[64 * 128];     // 16KB window of h1 (transposed)

    int bid  = blockIdx.x;
    int xcd  = bid & 7, idx = bid >> 3;
    int pair = xcd * 2 + (idx >> 5);  // (a,ks) pairs contiguous per XCD
    int mt   = idx & 31;
    int a    = pair & 3;
    int ks   = pair >> 2;

    int t    = threadIdx.x;
    int lane = t & 63, wn = t >> 6;          // 4 waves = 4 N-columns
    int l31  = lane & 31, hi = lane >> 5;
    int b0   = mt * BM;

    const char* tbb = (const char*)Tb + (size_t)a * NTILES * TILE_B;
    int nt    = (ks == 1) ? 66 : 65;
    int jbase = ks * 32;
    int jn    = (ks == 0 || ks == 2) ? 64 : 32;

    auto tile_at = [&](int tt) -> int {
        if (tt < 64) return ks * 64 + tt;
        if (ks == 0) return 256;
        if (ks == 1) return (tt == 64) ? 258 : 260;
        if (ks == 2) return 257;
        return 259;
    };

    // ---- one-time h1 window -> LDS (transposed, f16) ----
    {
        int row = t & 127, hs = t >> 7;
        const float* x1r = x1 + ((size_t)(b0 + row) * NA + a) * DDIM + jbase;
        int qn = jn >> 3;                         // 4 or 8 f32x4 loads per thread
        for (int q = hs * qn; q < (hs + 1) * qn; ++q) {
            f32x4 v = *(const f32x4*)(x1r + q * 4);
            #pragma unroll
            for (int e = 0; e < 4; ++e)
                h1t[(q * 4 + e) * 128 + row] = (f16)v[e];
        }
    }
    // ---- one-time h0 -> registers (4 rows/lane, windows split by hi) ----
    f16x8 h0reg[4][8];
    #pragma unroll
    for (int fm = 0; fm < 4; ++fm) {
        int row = b0 + fm * 32 + l31;
        const float* x0r = x0 + ((size_t)row * NA + a) * DDIM;
        #pragma unroll
        for (int w = 0; w < 8; ++w) {
            int wf = 2 * w + hi;
            f32x4 v0 = *(const f32x4*)(x0r + wf * 8);
            f32x4 v1 = *(const f32x4*)(x0r + wf * 8 + 4);
            f16x8 h;
            #pragma unroll
            for (int e = 0; e < 4; ++e) { h[e] = (f16)v0[e]; h[e + 4] = (f16)v1[e]; }
            h0reg[fm][w] = h;
        }
    }
    __syncthreads();   // h1t visible; only barrier in the kernel

    // per-lane B pointer (fragment layout == prep global layout)
    const char* bp = tbb + (size_t)(ks * 64) * TILE_B + hi * 2048 + (wn * 32 + l31) * 16;

    f16x8 bA[4], bB[4];
    #pragma unroll
    for (int kk = 0; kk < 4; ++kk) bA[kk] = *(const f16x8*)(bp + kk * 4096);
    #pragma unroll
    for (int kk = 0; kk < 4; ++kk) bB[kk] = *(const f16x8*)(bp + TILE_B + kk * 4096);

    f32x16 acc[4];
    #pragma unroll
    for (int i = 0; i < 4; ++i) acc[i] = (f32x16)0.f;

    // ---- main loop: 64 tiles, barrier-free, register double buffer ----
    #pragma unroll 1
    for (int p = 0; p < 32; ++p) {
        f16 h1v[4];
        #pragma unroll
        for (int fm = 0; fm < 4; ++fm)
            h1v[fm] = h1t[p * 128 + fm * 32 + l31];

        // tile 2p from bufA
        #pragma unroll
        for (int kk = 0; kk < 4; ++kk) {
            #pragma unroll
            for (int fm = 0; fm < 4; ++fm) {
                f16x8 af = h0reg[fm][kk] * h1v[fm];
                acc[fm] = __builtin_amdgcn_mfma_f32_32x32x16_f16(af, bA[kk], acc[fm], 0, 0, 0);
            }
        }
        {   // prefetch tile 2p+2 into bufA
            int nxt = 2 * p + 2; if (nxt > 63) nxt = 63;
            const char* q = bp + (size_t)nxt * TILE_B;
            #pragma unroll
            for (int kk = 0; kk < 4; ++kk) bA[kk] = *(const f16x8*)(q + kk * 4096);
        }
        // tile 2p+1 from bufB
        #pragma unroll
        for (int kk = 0; kk < 4; ++kk) {
            #pragma unroll
            for (int fm = 0; fm < 4; ++fm) {
                f16x8 af = h0reg[fm][4 + kk] * h1v[fm];
                acc[fm] = __builtin_amdgcn_mfma_f32_32x32x16_f16(af, bB[kk], acc[fm], 0, 0, 0);
            }
        }
        {   // prefetch tile 2p+3 into bufB
            int nxt = 2 * p + 3; if (nxt > 63) nxt = 63;
            const char* q = bp + (size_t)nxt * TILE_B;
            #pragma unroll
            for (int kk = 0; kk < 4; ++kk) bB[kk] = *(const f16x8*)(q + kk * 4096);
        }
    }

    // ---- correction tail (1-2 tiles, per-ks role), direct B loads ----
    for (int tt = 64; tt < nt; ++tt) {
        const char* q = tbb + (size_t)tile_at(tt) * TILE_B + hi * 2048 + (wn * 32 + l31) * 16;
        f16x8 bt[4];
        #pragma unroll
        for (int kk = 0; kk < 4; ++kk) bt[kk] = *(const f16x8*)(q + kk * 4096);
        bool icorr_lo = (ks == 1) && (tt == 64);

        #pragma unroll
        for (int kk = 0; kk < 4; ++kk) {
            #pragma unroll
            for (int fm = 0; fm < 4; ++fm) {
                f16x8 af;
                if (ks == 0 || ks == 2) {            // j-corr: G = h1[c]
                    int row = fm * 32 + l31;
                    #pragma unroll
                    for (int e = 0; e < 8; ++e)
                        af[e] = h1t[(kk * 16 + hi * 8 + e) * 128 + row];
                } else if (ks == 3) {                // i-corr hi: G = h0[64+c]
                    af = h0reg[fm][4 + kk];
                } else if (icorr_lo) {               // i-corr lo: G = h0[c]
                    af = h0reg[fm][kk];
                } else {                             // const tile: G = 1 at k_local 0
                    af = (f16x8)(f16)0.f;
                    if (kk == 0 && hi == 0) af[0] = (f16)1.f;
                }
                acc[fm] = __builtin_amdgcn_mfma_f32_32x32x16_f16(af, bt[kk], acc[fm], 0, 0, 0);
            }
        }
    }

    // ---- epilogue: C/D 32x32 layout col=lane&31, row=(r&3)+8*(r>>2)+4*hi ----
    float* base = ATOMIC ? dst : dst + (size_t)ks * OUT_ELEMS;
    #pragma unroll
    for (int fm = 0; fm < 4; ++fm)
        #pragma unroll
        for (int r = 0; r < 16; ++r) {
            int row = b0 + fm * 32 + (r & 3) + 8 * (r >> 2) + 4 * hi;
            int col = wn * 32 + l31;
            size_t off = ((size_t)row * NA + a) * OUTD + col;
            if (ATOMIC) unsafeAtomicAdd(&base[off], acc[fm][r]);
            else        base[off] = acc[fm][r];
        }
}

// ---------------------------------------------------------------------------
// Reduce: out = P0 + P1 + P2 + P3 (f32x4 vectorized)
// ---------------------------------------------------------------------------
__global__ __launch_bounds__(256) void reduce_kernel(const float* __restrict__ P,
                                                     float* __restrict__ out) {
    int i = blockIdx.x * 256 + threadIdx.x;     // 524288 vec4 elems
    f32x4 s = ((const f32x4*)P)[i];
    s += ((const f32x4*)(P + OUT_ELEMS))[i];
    s += ((const f32x4*)(P + 2 * (size_t)OUT_ELEMS))[i];
    s += ((const f32x4*)(P + 3 * (size_t)OUT_ELEMS))[i];
    ((f32x4*)out)[i] = s;
}

// ---------------------------------------------------------------------------
// Fallback (ws too small): naive but correct f32 kernel.
// ---------------------------------------------------------------------------
__global__ __launch_bounds__(128) void fallback_kernel(const float* __restrict__ x0,
                                                       const float* __restrict__ x1,
                                                       const float* __restrict__ T,
                                                       float* __restrict__ out) {
    int ba = blockIdx.x;
    int b = ba >> 2, a = ba & 3;
    int o = threadIdx.x;
    const float* h0 = x0 + ((size_t)b * NA + a) * DDIM;
    const float* h1 = x1 + ((size_t)b * NA + a) * DDIM;
    float acc = 0.f;
    for (int i = 0; i < 129; ++i) {
        float h0i = (i < 128) ? h0[i] : 1.f;
        const float* Trow = T + (((size_t)a * 129 + i) * 129) * 128 + o;
        float part = 0.f;
        for (int j = 0; j < 129; ++j) {
            float h1j = (j < 128) ? h1[j] : 1.f;
            part += h1j * Trow[(size_t)j * 128];
        }
        acc += h0i * part;
    }
    out[((size_t)b * NA + a) * OUTD + o] = acc;
}

extern "C" void kernel_launch(void* const* d_in, const int* in_sizes, int n_in,
                              void* d_out, int out_size, void* d_ws, size_t ws_size,
                              hipStream_t stream) {
    const float* x0 = (const float*)d_in[0];
    const float* x1 = (const float*)d_in[1];
    const float* T  = (const float*)d_in[2];
    float* out = (float*)d_out;

    if (ws_size < TB_BYTES) {
        fallback_kernel<<<4096 * NA, 128, 0, stream>>>(x0, x1, T, out);
        return;
    }

    f16* Tb = (f16*)d_ws;
    prep_kernel<<<NA * NTILES, 256, 0, stream>>>(T, Tb);

    if (ws_size >= WS_NEEDED) {
        float* P = (float*)((char*)d_ws + TB_BYTES);
        gemm_kernel<false><<<512, 256, 0, stream>>>(x0, x1, Tb, P);
        reduce_kernel<<<OUT_ELEMS / 4 / 256, 256, 0, stream>>>(P, out);
    } else {
        hipMemsetAsync(d_out, 0, (size_t)out_size * sizeof(float), stream);
        gemm_kernel<true><<<512, 256, 0, stream>>>(x0, x1, Tb, out);
    }
}